// Round 3
// baseline (242.934 us; speedup 1.0000x reference)
//
#include <hip/hip_runtime.h>
#include <hip/hip_bf16.h>

constexpr int N_NODES = 20000;
constexpr int N_EDGES = 50000;
constexpr int IN_DIM  = 512;
constexpr int D       = 32;

// Workspace layout (4-byte units):
constexpr size_t OFF_DEG    = 0;        // int[20480]
constexpr size_t OFF_CURSOR = 20480;    // int[20480]
constexpr size_t OFF_START  = 40960;    // int[20480]
constexpr size_t OFF_COL    = 61440;    // int2[100000] = 200000 ints
constexpr size_t OFF_A      = 262144;   // float[640000]
constexpr size_t OFF_B      = 262144 + 640000;

__device__ __forceinline__ float dot4(float4 a, float4 b) {
    return fmaf(a.x, b.x, fmaf(a.y, b.y, fmaf(a.z, b.z, a.w * b.w)));
}

// ---------------------------------------------------------------------------
// h = relu(x @ W + b) -> A ; fused integer degree histogram (40 slots/block)
__global__ __launch_bounds__(256) void k_proj(const float* __restrict__ x,
                                              const float* __restrict__ W,
                                              const float* __restrict__ b,
                                              const int* __restrict__ ei,
                                              float* __restrict__ A,
                                              int* __restrict__ deg) {
    __shared__ float xs[8][IN_DIM];
    const int tid  = threadIdx.x;
    const int row0 = blockIdx.x * 8;

    if (tid < 40) atomicAdd(&deg[ei[blockIdx.x * 40 + tid]], 1);

    const float4* xsrc = (const float4*)(x + (size_t)row0 * IN_DIM);
    float4* xdst = (float4*)&xs[0][0];
    #pragma unroll
    for (int i = 0; i < 4; ++i) xdst[tid + 256 * i] = xsrc[tid + 256 * i];
    __syncthreads();

    const int r = tid >> 5;
    const int c = tid & 31;
    const float* xr = xs[r];
    float acc = b[c];
    #pragma unroll 4
    for (int k = 0; k < IN_DIM; k += 4) {
        acc = fmaf(xr[k + 0], W[(k + 0) * D + c], acc);
        acc = fmaf(xr[k + 1], W[(k + 1) * D + c], acc);
        acc = fmaf(xr[k + 2], W[(k + 2) * D + c], acc);
        acc = fmaf(xr[k + 3], W[(k + 3) * D + c], acc);
    }
    A[(size_t)(row0 + r) * D + c] = fmaxf(acc, 0.0f);
}

// ---------------------------------------------------------------------------
// Exclusive prefix sum of deg[20000] -> start[20000]. One block, 1024 thr.
__global__ __launch_bounds__(1024) void k_scan(const int* __restrict__ deg,
                                               int* __restrict__ start) {
    __shared__ int sums[1024];
    const int tid  = threadIdx.x;
    const int base = tid * 20;
    int local[20];
    int s = 0;
    #pragma unroll
    for (int i = 0; i < 20; ++i) {
        const int idx = base + i;
        const int v = (idx < N_NODES) ? deg[idx] : 0;
        local[i] = v;
        s += v;
    }
    sums[tid] = s;
    __syncthreads();
    int acc = s;
    for (int off = 1; off < 1024; off <<= 1) {
        const int t = (tid >= off) ? sums[tid - off] : 0;
        __syncthreads();
        acc += t;
        sums[tid] = acc;
        __syncthreads();
    }
    int run = (tid > 0) ? sums[tid - 1] : 0;   // exclusive prefix
    #pragma unroll
    for (int i = 0; i < 20; ++i) {
        const int idx = base + i;
        if (idx < N_NODES) start[idx] = run;
        run += local[i];
    }
}

// ---------------------------------------------------------------------------
// Place each transport t into its out-node's incidence list: (t, in_node).
__global__ __launch_bounds__(256) void k_place(const int* __restrict__ ei,
                                               const int* __restrict__ start,
                                               int* __restrict__ cursor,
                                               int2* __restrict__ colpack) {
    const int t = blockIdx.x * 256 + threadIdx.x;
    if (t >= 2 * N_EDGES) return;
    const int* src = ei;
    const int* dst = ei + N_EDGES;
    const int e = (t < N_EDGES) ? t : t - N_EDGES;
    int in, out;
    if (t < N_EDGES) { in = src[e]; out = dst[e]; }
    else             { in = dst[e]; out = src[e]; }
    const int slot = atomicAdd(&cursor[out], 1);
    colpack[start[out] + slot] = make_int2(t, in);
}

// ---------------------------------------------------------------------------
// One wave per node: gather incident transports, y = T[t] @ h[in],
// acc = sum c_t*y, csum = sum c_t; then h' = h*(1-csum)+acc, LN, ReLU -> dest.
// T load mapping: instr j (0..3), lane l -> contiguous elem j*256 + l*4;
// row = j*8 + (l>>3), k-chunk = (l&7)*4.
__global__ __launch_bounds__(256) void k_node(const float* __restrict__ T,
                                              const float* __restrict__ rw,
                                              const float* __restrict__ alpha_p,
                                              const int* __restrict__ deg,
                                              const int* __restrict__ start,
                                              const int2* __restrict__ colpack,
                                              const float* __restrict__ hA,
                                              const float* __restrict__ gam,
                                              const float* __restrict__ bet,
                                              float* __restrict__ dest) {
    const int lane = threadIdx.x & 63;
    const int node = __builtin_amdgcn_readfirstlane(blockIdx.x * 4 + (threadIdx.x >> 6));
    const int d    = __builtin_amdgcn_readfirstlane(deg[node]);
    const int st   = __builtin_amdgcn_readfirstlane(start[node]);
    const int m    = lane & 7;
    const float alpha = alpha_p[0];

    float p0 = 0.f, p1 = 0.f, p2 = 0.f, p3 = 0.f, csum = 0.f;
    #pragma unroll 2
    for (int k = 0; k < d; ++k) {
        const int2 ci = colpack[st + k];
        const int t  = ci.x;
        const int in = ci.y;
        const float4* Tp = (const float4*)(T + (size_t)t * (D * D));
        const float4 a0 = Tp[lane], a1 = Tp[64 + lane], a2 = Tp[128 + lane], a3 = Tp[192 + lane];
        const float4 h  = ((const float4*)(hA + (size_t)in * D))[m];
        const float  c  = alpha * log1pf(expf(rw[t]));
        p0 = fmaf(c, dot4(a0, h), p0);
        p1 = fmaf(c, dot4(a1, h), p1);
        p2 = fmaf(c, dot4(a2, h), p2);
        p3 = fmaf(c, dot4(a3, h), p3);
        csum += c;
    }
    const float invdeg = 1.0f / fmaxf((float)d, 1.0f);

    // reduce over the 8-lane k-chunk group
    #define RED8(p) { p += __shfl_xor(p, 1); p += __shfl_xor(p, 2); p += __shfl_xor(p, 4); }
    RED8(p0) RED8(p1) RED8(p2) RED8(p3)
    #undef RED8

    // redistribute: dest lane r (<32) wants row r = j*8+g -> source lane g*8
    const int srcl = (lane & 7) * 8;
    const float v0 = __shfl(p0, srcl);
    const float v1 = __shfl(p1, srcl);
    const float v2 = __shfl(p2, srcl);
    const float v3 = __shfl(p3, srcl);

    if (lane < 32) {
        const float bacc = ((lane < 8) ? v0 : (lane < 16) ? v1 : (lane < 24) ? v2 : v3) * invdeg;
        const float sc   = csum * invdeg;
        const float hv   = hA[(size_t)node * D + lane];
        const float v    = hv * (1.0f - sc) + bacc;

        float s = v;
        #pragma unroll
        for (int msk = 16; msk >= 1; msk >>= 1) s += __shfl_xor(s, msk);
        const float mu = s * (1.0f / 32.0f);
        const float dv = v - mu;
        float q = dv * dv;
        #pragma unroll
        for (int msk = 16; msk >= 1; msk >>= 1) q += __shfl_xor(q, msk);
        const float var = q * (1.0f / 32.0f);

        float y = dv * rsqrtf(var + 1e-5f) * gam[lane] + bet[lane];
        dest[(size_t)node * D + lane] = fmaxf(y, 0.0f);
    }
}

// ---------------------------------------------------------------------------
extern "C" void kernel_launch(void* const* d_in, const int* in_sizes, int n_in,
                              void* d_out, int out_size, void* d_ws, size_t ws_size,
                              hipStream_t stream) {
    const float* x      = (const float*)d_in[0];
    const int*   ei     = (const int*)  d_in[1];   // [2, E]: src row | dst row
    const float* W      = (const float*)d_in[2];
    const float* b      = (const float*)d_in[3];
    const float* alpha0 = (const float*)d_in[4];
    const float* T0     = (const float*)d_in[5];
    const float* rw0    = (const float*)d_in[6];
    const float* g0     = (const float*)d_in[7];
    const float* be0    = (const float*)d_in[8];
    const float* alpha1 = (const float*)d_in[9];
    const float* T1     = (const float*)d_in[10];
    const float* rw1    = (const float*)d_in[11];
    const float* g1     = (const float*)d_in[12];
    const float* be1    = (const float*)d_in[13];

    float* out = (float*)d_out;
    int*   wsi = (int*)d_ws;
    float* wsf = (float*)d_ws;

    int*  deg    = wsi + OFF_DEG;
    int*  cursor = wsi + OFF_CURSOR;
    int*  start  = wsi + OFF_START;
    int2* colp   = (int2*)(wsi + OFF_COL);
    float* A     = wsf + OFF_A;
    float* B     = wsf + OFF_B;

    // zero deg + cursor in one memset
    hipMemsetAsync(wsi, 0, 2 * 20480 * sizeof(int), stream);

    k_proj <<<N_NODES / 8, 256, 0, stream>>>(x, W, b, ei, A, deg);
    k_scan <<<1, 1024, 0, stream>>>(deg, start);
    k_place<<<(2 * N_EDGES + 255) / 256, 256, 0, stream>>>(ei, start, cursor, colp);

    k_node<<<N_NODES / 4, 256, 0, stream>>>(T0, rw0, alpha0, deg, start, colp, A, g0, be0, B);
    k_node<<<N_NODES / 4, 256, 0, stream>>>(T1, rw1, alpha1, deg, start, colp, B, g1, be1, out);
}